// Round 2
// baseline (276.757 us; speedup 1.0000x reference)
//
#include <hip/hip_runtime.h>
#include <hip/hip_bf16.h>

#define N 2048
#define B 16
#define LOG2E 1.44269504088896340736f

typedef float v4f __attribute__((ext_vector_type(4)));

// Kernel 1: asum2[b,i] = LOG2E * sum_k |s[b,i] - s[b,k]|
__global__ __launch_bounds__(256) void asum_kernel(const float* __restrict__ s,
                                                   float* __restrict__ asum2) {
    const int b = blockIdx.y;
    const int chunk = blockIdx.x;

    __shared__ float row[N];
    __shared__ float partial[256];
    const v4f* g4 = (const v4f*)(s + b * N);
    v4f* r4 = (v4f*)row;
    r4[threadIdx.x] = g4[threadIdx.x];
    r4[threadIdx.x + 256] = g4[threadIdx.x + 256];
    __syncthreads();

    const int il = threadIdx.x & 127;
    const int half = threadIdx.x >> 7;   // wave-uniform
    const int i = chunk * 128 + il;
    const float si = row[i];
    const v4f* row4 = (const v4f*)(row + half * (N / 2));
    float acc = 0.0f;
#pragma unroll 4
    for (int k = 0; k < N / 8; ++k) {
        v4f rv = row4[k];
        acc += fabsf(si - rv.x) + fabsf(si - rv.y) +
               fabsf(si - rv.z) + fabsf(si - rv.w);
    }
    partial[threadIdx.x] = acc;
    __syncthreads();
    if (threadIdx.x < 128)
        asum2[b * N + i] = LOG2E * (partial[threadIdx.x] + partial[threadIdx.x + 128]);
}

// Kernel 2 (rowstat): per output row (b,j) compute
//   m2[b,j] = max_i (ls_i * c_j - la_i)          (log2-domain)
//   r2[b,j] = 1 / sum_i exp2(x_i - m)
// Proven reduction structure: 4 waves x 2 rows x 4 groups = 32 rows/block.
// grid = (N/32, B), block = 256.
__global__ __launch_bounds__(256) void rowstat_kernel(const float* __restrict__ s,
                                                      const float* __restrict__ asum2,
                                                      float* __restrict__ m2,
                                                      float* __restrict__ r2) {
    __shared__ float ls[N];   // s * LOG2E
    __shared__ float la[N];   // asum2 (LOG2E already folded)

    const int t = threadIdx.x;
    const int lane = t & 63;
    const int wave = t >> 6;
    const int b = blockIdx.y;

    {
        const v4f* g4 = (const v4f*)(s + (size_t)b * N);
        const v4f* ga4 = (const v4f*)(asum2 + (size_t)b * N);
        v4f* l4 = (v4f*)ls;
        v4f* m4 = (v4f*)la;
        v4f s0 = g4[t], s1 = g4[t + 256];
        v4f a0 = ga4[t], a1 = ga4[t + 256];
        s0 *= LOG2E; s1 *= LOG2E;
        l4[t] = s0; l4[t + 256] = s1;
        m4[t] = a0; m4[t + 256] = a1;
    }
    __syncthreads();

    const v4f* ls4 = (const v4f*)ls;
    const v4f* la4 = (const v4f*)la;
    const int base = blockIdx.x * 32;

#pragma unroll 1
    for (int g = 0; g < 4; ++g) {
        const int jA = base + g * 8 + wave;
        const int jB = jA + 4;
        const float cA = (float)(N - 1 - 2 * jA);
        const float cB = (float)(N - 1 - 2 * jB);

        float va[32], vb[32];
#pragma unroll
        for (int c = 0; c < 8; ++c) {
            v4f sv = ls4[c * 64 + lane];
            v4f av = la4[c * 64 + lane];
            va[c * 4 + 0] = sv.x * cA - av.x;  vb[c * 4 + 0] = sv.x * cB - av.x;
            va[c * 4 + 1] = sv.y * cA - av.y;  vb[c * 4 + 1] = sv.y * cB - av.y;
            va[c * 4 + 2] = sv.z * cA - av.z;  vb[c * 4 + 2] = sv.z * cB - av.z;
            va[c * 4 + 3] = sv.w * cA - av.w;  vb[c * 4 + 3] = sv.w * cB - av.w;
        }

        float mA = va[0], mB = vb[0];
#pragma unroll
        for (int i = 1; i < 32; ++i) { mA = fmaxf(mA, va[i]); mB = fmaxf(mB, vb[i]); }
#pragma unroll
        for (int off = 32; off >= 1; off >>= 1) {
            mA = fmaxf(mA, __shfl_xor(mA, off));
            mB = fmaxf(mB, __shfl_xor(mB, off));
        }

        float sA = 0.0f, sB = 0.0f;
#pragma unroll
        for (int i = 0; i < 32; ++i) {
            sA += __builtin_amdgcn_exp2f(va[i] - mA);
            sB += __builtin_amdgcn_exp2f(vb[i] - mB);
        }
#pragma unroll
        for (int off = 32; off >= 1; off >>= 1) {
            sA += __shfl_xor(sA, off);
            sB += __shfl_xor(sB, off);
        }

        if (lane == 0) {
            m2[(size_t)b * N + jA] = mA;
            r2[(size_t)b * N + jA] = 1.0f / sA;
            m2[(size_t)b * N + jB] = mB;
            r2[(size_t)b * N + jB] = 1.0f / sB;
        }
    }
}

// Kernel 3 (stream): pure streaming write. Each block owns 16 consecutive
// output rows (128 KB contiguous). Each thread owns 8 fixed columns
// (cols 4t..4t+3 and 1024+4t..), held in registers across all 16 rows.
// No LDS, no barriers, no cross-lane ops — per element: fma, sub, exp2, mul.
// grid = (N/16, B), block = 256.
__global__ __launch_bounds__(256) void stream_kernel(const float* __restrict__ s,
                                                     const float* __restrict__ asum2,
                                                     const float* __restrict__ m2,
                                                     const float* __restrict__ r2,
                                                     float* __restrict__ out) {
    const int t = threadIdx.x;
    const int b = blockIdx.y;
    const int jbase = blockIdx.x * 16;

    const float* sb = s + (size_t)b * N;
    const float* ab = asum2 + (size_t)b * N;
    v4f s0 = *(const v4f*)(sb + 4 * t);
    v4f s1 = *(const v4f*)(sb + 1024 + 4 * t);
    v4f a0 = *(const v4f*)(ab + 4 * t);
    v4f a1 = *(const v4f*)(ab + 1024 + 4 * t);
    s0 *= LOG2E; s1 *= LOG2E;

    // row stats for this block's 16 rows (uniform addresses -> L1 broadcast)
    const v4f* mp = (const v4f*)(m2 + (size_t)b * N + jbase);
    const v4f* rp = (const v4f*)(r2 + (size_t)b * N + jbase);
    float mv[16], rv[16];
#pragma unroll
    for (int q = 0; q < 4; ++q) {
        v4f tm = mp[q];
        v4f tr = rp[q];
        mv[q * 4 + 0] = tm.x; mv[q * 4 + 1] = tm.y;
        mv[q * 4 + 2] = tm.z; mv[q * 4 + 3] = tm.w;
        rv[q * 4 + 0] = tr.x; rv[q * 4 + 1] = tr.y;
        rv[q * 4 + 2] = tr.z; rv[q * 4 + 3] = tr.w;
    }

    float* ob = out + ((size_t)b * N + jbase) * N;

#pragma unroll
    for (int rr = 0; rr < 16; ++rr) {
        const float cj = (float)(N - 1 - 2 * (jbase + rr));
        const float m = mv[rr];
        const float r = rv[rr];
        v4f x0 = s0 * cj - a0;
        v4f x1 = s1 * cj - a1;
        v4f e0, e1;
        e0.x = __builtin_amdgcn_exp2f(x0.x - m) * r;
        e0.y = __builtin_amdgcn_exp2f(x0.y - m) * r;
        e0.z = __builtin_amdgcn_exp2f(x0.z - m) * r;
        e0.w = __builtin_amdgcn_exp2f(x0.w - m) * r;
        e1.x = __builtin_amdgcn_exp2f(x1.x - m) * r;
        e1.y = __builtin_amdgcn_exp2f(x1.y - m) * r;
        e1.z = __builtin_amdgcn_exp2f(x1.z - m) * r;
        e1.w = __builtin_amdgcn_exp2f(x1.w - m) * r;
        float* op = ob + (size_t)rr * N;
        *(v4f*)(op + 4 * t) = e0;
        *(v4f*)(op + 1024 + 4 * t) = e1;
    }
}

extern "C" void kernel_launch(void* const* d_in, const int* in_sizes, int n_in,
                              void* d_out, int out_size, void* d_ws, size_t ws_size,
                              hipStream_t stream) {
    const float* scores = (const float*)d_in[0];
    float* out = (float*)d_out;
    float* asum2 = (float*)d_ws;                     // B*N floats = 128 KB
    float* m2 = (float*)d_ws + (size_t)B * N;        // 128 KB
    float* r2 = (float*)d_ws + 2 * (size_t)B * N;    // 128 KB

    dim3 g1(N / 128, B);
    asum_kernel<<<g1, 256, 0, stream>>>(scores, asum2);

    dim3 g2(N / 32, B);
    rowstat_kernel<<<g2, 256, 0, stream>>>(scores, asum2, m2, r2);

    dim3 g3(N / 16, B);
    stream_kernel<<<g3, 256, 0, stream>>>(scores, asum2, m2, r2, out);
}

// Round 3
// 263.514 us; speedup vs baseline: 1.0503x; 1.0503x over previous
//
#include <hip/hip_runtime.h>
#include <hip/hip_bf16.h>

#define N 2048
#define B 16
#define LOG2E 1.44269504088896340736f

typedef float v4f __attribute__((ext_vector_type(4)));

// Kernel 1: asum2[b,i] = LOG2E * sum_k |s[b,i] - s[b,k]|
__global__ __launch_bounds__(256) void asum_kernel(const float* __restrict__ s,
                                                   float* __restrict__ asum2) {
    const int b = blockIdx.y;
    const int chunk = blockIdx.x;

    __shared__ float row[N];
    __shared__ float partial[256];
    const v4f* g4 = (const v4f*)(s + b * N);
    v4f* r4 = (v4f*)row;
    r4[threadIdx.x] = g4[threadIdx.x];
    r4[threadIdx.x + 256] = g4[threadIdx.x + 256];
    __syncthreads();

    const int il = threadIdx.x & 127;
    const int half = threadIdx.x >> 7;   // wave-uniform
    const int i = chunk * 128 + il;
    const float si = row[i];
    const v4f* row4 = (const v4f*)(row + half * (N / 2));
    float acc = 0.0f;
#pragma unroll 4
    for (int k = 0; k < N / 8; ++k) {
        v4f rv = row4[k];
        acc += fabsf(si - rv.x) + fabsf(si - rv.y) +
               fabsf(si - rv.z) + fabsf(si - rv.w);
    }
    partial[threadIdx.x] = acc;
    __syncthreads();
    if (threadIdx.x < 128)
        asum2[b * N + i] = LOG2E * (partial[threadIdx.x] + partial[threadIdx.x + 128]);
}

// Kernel 2: 8 rows per block; each wave processes TWO independent rows
// (jA = base+wave, jB = base+wave+4) interleaved for ILP — row B's fma/exp
// fills row A's shuffle-latency bubbles. s/asum2 staged in LDS once per
// 8 rows. grid = (N/8, B), block = 256.
__global__ __launch_bounds__(256) void softmax_rows(const float* __restrict__ s,
                                                    const float* __restrict__ asum2,
                                                    float* __restrict__ out) {
    __shared__ float ls[N];   // s * LOG2E
    __shared__ float la[N];   // asum2 (LOG2E already folded)

    const int t = threadIdx.x;
    const int lane = t & 63;
    const int wave = t >> 6;
    const int b = blockIdx.y;
    const int jA = blockIdx.x * 8 + wave;
    const int jB = jA + 4;

    {
        const v4f* g4 = (const v4f*)(s + (size_t)b * N);
        const v4f* ga4 = (const v4f*)(asum2 + (size_t)b * N);
        v4f* l4 = (v4f*)ls;
        v4f* m4 = (v4f*)la;
        v4f s0 = g4[t], s1 = g4[t + 256];
        v4f a0 = ga4[t], a1 = ga4[t + 256];
        s0 *= LOG2E; s1 *= LOG2E;
        l4[t] = s0; l4[t + 256] = s1;
        m4[t] = a0; m4[t + 256] = a1;
    }
    __syncthreads();

    const float cA = (float)(N - 1 - 2 * jA);
    const float cB = (float)(N - 1 - 2 * jB);

    const v4f* ls4 = (const v4f*)ls;
    const v4f* la4 = (const v4f*)la;

    float va[32], vb[32];
#pragma unroll
    for (int c = 0; c < 8; ++c) {
        v4f sv = ls4[c * 64 + lane];
        v4f av = la4[c * 64 + lane];
        va[c * 4 + 0] = sv.x * cA - av.x;  vb[c * 4 + 0] = sv.x * cB - av.x;
        va[c * 4 + 1] = sv.y * cA - av.y;  vb[c * 4 + 1] = sv.y * cB - av.y;
        va[c * 4 + 2] = sv.z * cA - av.z;  vb[c * 4 + 2] = sv.z * cB - av.z;
        va[c * 4 + 3] = sv.w * cA - av.w;  vb[c * 4 + 3] = sv.w * cB - av.w;
    }

    // interleaved max reductions
    float mA = va[0], mB = vb[0];
#pragma unroll
    for (int i = 1; i < 32; ++i) { mA = fmaxf(mA, va[i]); mB = fmaxf(mB, vb[i]); }
#pragma unroll
    for (int off = 32; off >= 1; off >>= 1) {
        mA = fmaxf(mA, __shfl_xor(mA, off));
        mB = fmaxf(mB, __shfl_xor(mB, off));
    }

    // interleaved exp2 + sum reductions
    float sA = 0.0f, sB = 0.0f;
#pragma unroll
    for (int i = 0; i < 32; ++i) {
        va[i] = __builtin_amdgcn_exp2f(va[i] - mA);  sA += va[i];
        vb[i] = __builtin_amdgcn_exp2f(vb[i] - mB);  sB += vb[i];
    }
#pragma unroll
    for (int off = 32; off >= 1; off >>= 1) {
        sA += __shfl_xor(sA, off);
        sB += __shfl_xor(sB, off);
    }

    const float rA = 1.0f / sA;
    const float rB = 1.0f / sB;

    v4f* oA = (v4f*)(out + ((size_t)b * N + jA) * N);
    v4f* oB = (v4f*)(out + ((size_t)b * N + jB) * N);
#pragma unroll
    for (int c = 0; c < 8; ++c) {
        v4f o;
        o.x = va[c * 4 + 0] * rA; o.y = va[c * 4 + 1] * rA;
        o.z = va[c * 4 + 2] * rA; o.w = va[c * 4 + 3] * rA;
        oA[c * 64 + lane] = o;
        v4f p;
        p.x = vb[c * 4 + 0] * rB; p.y = vb[c * 4 + 1] * rB;
        p.z = vb[c * 4 + 2] * rB; p.w = vb[c * 4 + 3] * rB;
        oB[c * 64 + lane] = p;
    }
}

extern "C" void kernel_launch(void* const* d_in, const int* in_sizes, int n_in,
                              void* d_out, int out_size, void* d_ws, size_t ws_size,
                              hipStream_t stream) {
    const float* scores = (const float*)d_in[0];
    float* out = (float*)d_out;
    float* asum2 = (float*)d_ws;   // B*N*4 = 128 KB

    dim3 g1(N / 128, B);
    asum_kernel<<<g1, 256, 0, stream>>>(scores, asum2);

    dim3 g2(N / 8, B);
    softmax_rows<<<g2, 256, 0, stream>>>(scores, asum2, out);
}